// Round 1
// baseline (1043.470 us; speedup 1.0000x reference)
//
#include <hip/hip_runtime.h>
#include <hip/hip_bf16.h>

// EdgePredictorGNN: 2-layer GCN + edge MLP.
// N=50000 nodes, in_c=128, hid=64, out_c=16, E=800000 edges.

#define IN_C 128
#define HID 64
#define OUT_C 16

// ---------------- CSR build ----------------

__global__ void k_init_cnt(int* __restrict__ cnt, int n) {
    int i = blockIdx.x * blockDim.x + threadIdx.x;
    if (i < n) cnt[i] = 0;
}

__global__ void k_count(const int* __restrict__ ei, int* __restrict__ cnt, int e) {
    int i = blockIdx.x * blockDim.x + threadIdx.x;
    if (i < e) atomicAdd(&cnt[ei[e + i]], 1);   // dst = ei[1][i]
}

// block-wide inclusive scan (1024 threads/block)
__global__ __launch_bounds__(1024) void k_scan1(const int* __restrict__ cnt,
                                                int* __restrict__ tmp,
                                                int* __restrict__ bsum, int n) {
    __shared__ int s[1024];
    int i = blockIdx.x * 1024 + threadIdx.x;
    int v = (i < n) ? cnt[i] : 0;
    s[threadIdx.x] = v;
    __syncthreads();
    for (int off = 1; off < 1024; off <<= 1) {
        int add = (threadIdx.x >= off) ? s[threadIdx.x - off] : 0;
        __syncthreads();
        s[threadIdx.x] += add;
        __syncthreads();
    }
    if (i < n) tmp[i] = s[threadIdx.x];
    if (threadIdx.x == 1023) bsum[blockIdx.x] = s[1023];
}

__global__ void k_scan2(int* __restrict__ bsum, int nb) {
    if (blockIdx.x == 0 && threadIdx.x == 0) {
        int run = 0;
        for (int b = 0; b < nb; ++b) { int v = bsum[b]; bsum[b] = run; run += v; }
    }
}

__global__ void k_scan3(const int* __restrict__ cnt, const int* __restrict__ tmp,
                        const int* __restrict__ bsum, int* __restrict__ rowptr,
                        int* __restrict__ cur, float* __restrict__ dinv, int n, int e) {
    int i = blockIdx.x * blockDim.x + threadIdx.x;
    if (i < n) {
        int excl = tmp[i] - cnt[i] + bsum[i >> 10];
        rowptr[i] = excl;
        cur[i] = excl;
        dinv[i] = 1.0f / sqrtf((float)(cnt[i] + 1));  // +1 self loop
        if (i == 0) rowptr[n] = e;
    }
}

__global__ void k_scatter(const int* __restrict__ ei, int* __restrict__ cur,
                          int* __restrict__ csrc, int e) {
    int i = blockIdx.x * blockDim.x + threadIdx.x;
    if (i < e) {
        int s = ei[i];
        int d = ei[e + i];
        int p = atomicAdd(&cur[d], 1);
        csrc[p] = s;
    }
}

// ---------------- node GEMM: T = A @ W  (W is [K,64]) ----------------
// one wave per block; lane = output col; weights stationary in VGPRs;
// A-row accesses are wave-uniform -> scalar loads.

template <int K>
__global__ __launch_bounds__(64) void k_gemm_node(const float* __restrict__ A,
                                                  const float* __restrict__ W,
                                                  float* __restrict__ T,
                                                  int n, int npb) {
    int lane = threadIdx.x;
    float w[K];
#pragma unroll
    for (int k = 0; k < K; ++k) w[k] = W[k * 64 + lane];
    int n0 = blockIdx.x * npb;
    int n1 = n0 + npb; if (n1 > n) n1 = n;
#pragma unroll 1
    for (int i = n0; i < n1; ++i) {
        const float* a = A + (size_t)i * K;
        float acc = 0.f;
#pragma unroll
        for (int k = 0; k < K; ++k) acc = fmaf(a[k], w[k], acc);
        T[(size_t)i * 64 + lane] = acc;
    }
}

// ---------------- GCN aggregation ----------------
// h[n] = relu(b + dinv[n] * (t[n]*dinv[n] + sum_s t[s]*dinv[s]))
__global__ __launch_bounds__(64) void k_agg(const float* __restrict__ T,
                                            const int* __restrict__ rowptr,
                                            const int* __restrict__ csrc,
                                            const float* __restrict__ dinv,
                                            const float* __restrict__ bias,
                                            float* __restrict__ H, int n) {
    int nid = blockIdx.x;
    int lane = threadIdx.x;
    float dn = dinv[nid];
    float acc = T[(size_t)nid * 64 + lane] * dn;   // self loop
    int p0 = rowptr[nid], p1 = rowptr[nid + 1];
#pragma unroll 1
    for (int p = p0; p < p1; ++p) {
        int s = csrc[p];
        acc = fmaf(T[(size_t)s * 64 + lane], dinv[s], acc);
    }
    H[(size_t)nid * 64 + lane] = fmaxf(fmaf(dn, acc, bias[lane]), 0.f);
}

// ---------------- edge MLP ----------------
// out[e] = relu(concat(h[r],h[c]) @ Wm1 + bm1) @ Wm2 + bm2
// one wave/block, 64 edges/block. Stage1: lane = z-col, edge uniform,
// h-row via uniform (scalar) loads, Wm1 stationary in VGPRs.
// Stage2: LDS transpose (pitch 65), lane = edge, Wm2 via uniform loads.
__global__ __launch_bounds__(64) void k_mlp(const float* __restrict__ H,
                                            const int* __restrict__ ei,
                                            const float* __restrict__ Wm1,
                                            const float* __restrict__ bm1,
                                            const float* __restrict__ Wm2,
                                            const float* __restrict__ bm2,
                                            float* __restrict__ out,
                                            int e) {
    int lane = threadIdx.x;
    float w1a[64], w1b[64];
#pragma unroll
    for (int k = 0; k < 64; ++k) w1a[k] = Wm1[k * 64 + lane];
#pragma unroll
    for (int k = 0; k < 64; ++k) w1b[k] = Wm1[(64 + k) * 64 + lane];
    float bz = bm1[lane];
    __shared__ float zb[64 * 65];

    int e0 = blockIdx.x * 64;
#pragma unroll 1
    for (int ee = 0; ee < 64; ++ee) {
        int eid = e0 + ee;           // wave-uniform
        float z = 0.f;
        if (eid < e) {
            int r = ei[eid];
            int c = ei[e + eid];
            const float* hr = H + (size_t)r * 64;
            const float* hc = H + (size_t)c * 64;
            float acc = bz;
#pragma unroll
            for (int k = 0; k < 64; ++k) acc = fmaf(hr[k], w1a[k], acc);
#pragma unroll
            for (int k = 0; k < 64; ++k) acc = fmaf(hc[k], w1b[k], acc);
            z = fmaxf(acc, 0.f);
        }
        zb[ee * 65 + lane] = z;
    }
    __syncthreads();

    int eid = e0 + lane;
    float o[16];
#pragma unroll
    for (int i = 0; i < 16; ++i) o[i] = bm2[i];
#pragma unroll 4
    for (int j = 0; j < 64; ++j) {
        float zv = zb[lane * 65 + j];
#pragma unroll
        for (int i = 0; i < 16; ++i) o[i] = fmaf(zv, Wm2[j * 16 + i], o[i]);
    }
    if (eid < e) {
        float4* op = (float4*)(out + (size_t)eid * 16);
        op[0] = make_float4(o[0], o[1], o[2], o[3]);
        op[1] = make_float4(o[4], o[5], o[6], o[7]);
        op[2] = make_float4(o[8], o[9], o[10], o[11]);
        op[3] = make_float4(o[12], o[13], o[14], o[15]);
    }
}

// ---------------- launch ----------------

extern "C" void kernel_launch(void* const* d_in, const int* in_sizes, int n_in,
                              void* d_out, int out_size, void* d_ws, size_t ws_size,
                              hipStream_t stream) {
    const float* x   = (const float*)d_in[0];
    const int*   ei  = (const int*)d_in[1];
    const float* W1  = (const float*)d_in[2];
    const float* b1  = (const float*)d_in[3];
    const float* W2  = (const float*)d_in[4];
    const float* b2  = (const float*)d_in[5];
    const float* Wm1 = (const float*)d_in[6];
    const float* bm1 = (const float*)d_in[7];
    const float* Wm2 = (const float*)d_in[8];
    const float* bm2 = (const float*)d_in[9];
    float* out = (float*)d_out;

    int n = in_sizes[0] / IN_C;       // 50000
    int e = in_sizes[1] / 2;          // 800000

    // workspace layout
    char* w = (char*)d_ws;
    int* cnt    = (int*)w;                 w += (size_t)n * 4;
    int* tmp    = (int*)w;                 w += (size_t)n * 4;
    int* bsum   = (int*)w;                 w += 256 * 4;
    int* rowptr = (int*)w;                 w += (size_t)(n + 1) * 4;
    int* cur    = (int*)w;                 w += (size_t)n * 4;
    float* dinv = (float*)w;               w += (size_t)n * 4;
    int* csrc   = (int*)w;                 w += (size_t)e * 4;
    float* t    = (float*)w;               w += (size_t)n * HID * 4;
    float* h1   = (float*)w;               w += (size_t)n * HID * 4;
    float* h2   = (float*)w;               w += (size_t)n * HID * 4;

    int nb_n256 = (n + 255) / 256;
    int nb_e256 = (e + 255) / 256;
    int nb_scan = (n + 1023) / 1024;

    k_init_cnt<<<nb_n256, 256, 0, stream>>>(cnt, n);
    k_count<<<nb_e256, 256, 0, stream>>>(ei, cnt, e);
    k_scan1<<<nb_scan, 1024, 0, stream>>>(cnt, tmp, bsum, n);
    k_scan2<<<1, 64, 0, stream>>>(bsum, nb_scan);
    k_scan3<<<nb_n256, 256, 0, stream>>>(cnt, tmp, bsum, rowptr, cur, dinv, n, e);
    k_scatter<<<nb_e256, 256, 0, stream>>>(ei, cur, csrc, e);

    const int NPB = 32;
    int nb_gemm = (n + NPB - 1) / NPB;
    // layer 1
    k_gemm_node<IN_C><<<nb_gemm, 64, 0, stream>>>(x, W1, t, n, NPB);
    k_agg<<<n, 64, 0, stream>>>(t, rowptr, csrc, dinv, b1, h1, n);
    // layer 2
    k_gemm_node<HID><<<nb_gemm, 64, 0, stream>>>(h1, W2, t, n, NPB);
    k_agg<<<n, 64, 0, stream>>>(t, rowptr, csrc, dinv, b2, h2, n);
    // edge MLP
    int nb_mlp = (e + 63) / 64;
    k_mlp<<<nb_mlp, 64, 0, stream>>>(h2, ei, Wm1, bm1, Wm2, bm2, out, e);
}